// Round 6
// baseline (242.645 us; speedup 1.0000x reference)
//
#include <hip/hip_runtime.h>
#include <math.h>

// Fused AntiAliasActivation: up2 (12-tap polyphase) -> snake -> down2 (12-tap)
// x: (B=16, C=512, T=4096) fp32, out: same shape.
//
// R7: hybrid of R3 (LDS staging) and R6 (register rolling compute).
// R6 (83.5us) was limited by strided VMEM: per-lane 64B-stride dwordx4
// loads/stores span 4KB/wave-instr while touching 1KB -> ~4x TA work,
// exposed latency at 4 waves/SIMD. R7 makes ALL global traffic dense
// coalesced (16B/lane) via an LDS bounce in each direction, keeping the
// hardware-verified R6 compute core byte-identical:
//   stage x row (+8 halo) -> swizzled LDS -> 8x ds_read_b128 per thread
//   -> rolling compute in regs -> swizzled LDS -> coalesced stores.
// XOR swizzle byte^=((byte>>7)&7)<<4: the 64B-lane-stride b128 access
// (8-way bank conflict linear) becomes <=2-way (free, m136); the
// 16B-stride dense accesses stay conflict-free. Involution, preserves
// 16B granules.
//
// Phase-plane formulation (hardware-verified R3..R6):
//   E[s] = act( 2*sum_m x[clamp(s-3+m)]*u[11-2m] )   (yact[2s])
//   O[s] = act( 2*sum_m x[clamp(s-2+m)]*u[10-2m] )   (yact[2s+1])
//   out[o] = sum_m E[o-2+m]*d[2m+1] + sum_m O[o-3+m]*d[2m]
//   act(y) = y + rb*sin(y*ea)^2
// Per thread (o0 = 16*t): f[j] = x[clamp(o0-8+j)] (j=0..31, from LDS);
// activation i=0..20: ev=E[o0-2+i], ov=O[o0-3+i], window f[i+3..i+8];
// contribution of i to acc[r]: r in [i-5,i]&[0,15], taps d[2(i-r)+1]
// (E) / d[2(i-r)] (O). Down-conv pad clamp: lo (t=0) skip i<2 + patch
// at i=2 with E[0]; hi (t=255) override ev/ov with O[T-1] from i=18.

#define T_LEN 4096
#define NT    256
#define W     16                  // outputs per thread; NT*W == T_LEN
#define LDSF  4112                // 4096 + 8 halo each side
#define NQ_IN 1028                // LDSF / 4
#define NQ_OUT 1024               // T_LEN / 4

#define SWZ(b) ((b) ^ ((((b) >> 7) & 7) << 4))

__global__ __launch_bounds__(NT, 4) void aa_act_kernel(
    const float* __restrict__ x,
    const float* __restrict__ alpha,
    const float* __restrict__ beta,
    const float* __restrict__ upf,
    const float* __restrict__ downf,
    float* __restrict__ out,
    int C)
{
    __shared__ __align__(16) float sx[LDSF];

    const int t   = threadIdx.x;
    const int row = blockIdx.x;
    const int c   = row % C;

    const float* __restrict__ xr = x + (size_t)row * T_LEN;
    float* __restrict__ outr     = out + (size_t)row * T_LEN;

    // Uniform filter taps. Prescale up-filter by 2 (UP factor) — exact.
    float ue[6], uo[6], d[12];
#pragma unroll
    for (int m = 0; m < 6; ++m) {
        ue[m] = 2.0f * upf[11 - 2 * m];
        uo[m] = 2.0f * upf[10 - 2 * m];
    }
#pragma unroll
    for (int i = 0; i < 12; ++i) d[i] = downf[i];

    const float ea = __expf(alpha[c]);
    const float rb = 1.0f / (__expf(beta[c]) + 1e-9f);

    const bool lo = (t == 0);
    const bool hi = (t == NT - 1);

    // ---- Stage-in: LDS float j <- x[clamp(j-8)], dense coalesced ----
    for (int q = t; q < NQ_IN; q += NT) {
        const int gi = 4 * q - 8;
        float4 v;
        if (gi >= 0 && gi <= T_LEN - 4) {
            v = *(const float4*)(xr + gi);
        } else {
            v.x = xr[min(max(gi + 0, 0), T_LEN - 1)];
            v.y = xr[min(max(gi + 1, 0), T_LEN - 1)];
            v.z = xr[min(max(gi + 2, 0), T_LEN - 1)];
            v.w = xr[min(max(gi + 3, 0), T_LEN - 1)];
        }
        *(float4*)((char*)sx + SWZ(16 * q)) = v;
    }
    __syncthreads();

    // ---- f[0..31] = x[clamp(o0-8 .. o0+23)] via swizzled b128 ----
    float f[32];
#pragma unroll
    for (int i = 0; i < 8; ++i) {
        float4 v = *(const float4*)((const char*)sx + SWZ(64 * t + 16 * i));
        f[4 * i + 0] = v.x; f[4 * i + 1] = v.y;
        f[4 * i + 2] = v.z; f[4 * i + 3] = v.w;
    }

    float acc[W];
#pragma unroll
    for (int r = 0; r < W; ++r) acc[r] = 0.0f;

    float Rv = 0.0f;   // O[T-1] capture (hi lane only)

#pragma unroll
    for (int i = 0; i < 21; ++i) {
        // activation pair at rolling index i
        float ye = f[i + 3] * ue[0];
        ye = fmaf(f[i + 4], ue[1], ye);
        ye = fmaf(f[i + 5], ue[2], ye);
        ye = fmaf(f[i + 6], ue[3], ye);
        ye = fmaf(f[i + 7], ue[4], ye);
        ye = fmaf(f[i + 8], ue[5], ye);
        float yo = f[i + 3] * uo[0];
        yo = fmaf(f[i + 4], uo[1], yo);
        yo = fmaf(f[i + 5], uo[2], yo);
        yo = fmaf(f[i + 6], uo[3], yo);
        yo = fmaf(f[i + 7], uo[4], yo);
        yo = fmaf(f[i + 8], uo[5], yo);
        float se = __sinf(ye * ea);
        float so = __sinf(yo * ea);
        float ev = fmaf(rb * se, se, ye);
        float ov = fmaf(rb * so, so, yo);

        // ---- down-conv pad-clamp overrides (row edges) ----
        if (i == 18) {
            if (hi) { Rv = ov; ev = ov; }          // e[18] := O[T-1]
        }
        if (i >= 19) {
            if (hi) { ev = Rv; ov = Rv; }          // e/o[19..20] := O[T-1]
        }
        if (i == 2) {
            if (lo) {
                // ev == E[0]; patch the skipped i=0,1 contributions
                acc[0] = fmaf(ev, d[0] + d[1] + d[2] + d[3], acc[0]);
                acc[1] = fmaf(ev, d[0] + d[1], acc[1]);
                ov = ev;                            // o_[2] := E[0]
            }
        }

        // ---- consume into accumulators: r in [i-5, i] & [0, 15] ----
        const int rlo = (i - 5 > 0) ? (i - 5) : 0;
        const int rhi = (i < W - 1) ? i : (W - 1);
        if (i < 2) {
            if (!lo) {
#pragma unroll
                for (int r = rlo; r <= rhi; ++r)
                    acc[r] = fmaf(ev, d[2 * (i - r) + 1],
                             fmaf(ov, d[2 * (i - r)], acc[r]));
            }
        } else {
#pragma unroll
            for (int r = rlo; r <= rhi; ++r)
                acc[r] = fmaf(ev, d[2 * (i - r) + 1],
                         fmaf(ov, d[2 * (i - r)], acc[r]));
        }
    }

    // ---- transpose out through LDS: acc -> LDS float 16t+r ----
    __syncthreads();   // all f-reads done before buffer reuse
#pragma unroll
    for (int i = 0; i < 4; ++i)
        *(float4*)((char*)sx + SWZ(64 * t + 16 * i)) =
            make_float4(acc[4 * i + 0], acc[4 * i + 1],
                        acc[4 * i + 2], acc[4 * i + 3]);
    __syncthreads();

    // ---- dense coalesced stores ----
    for (int q = t; q < NQ_OUT; q += NT) {
        float4 v = *(const float4*)((const char*)sx + SWZ(16 * q));
        ((float4*)outr)[q] = v;
    }
}

extern "C" void kernel_launch(void* const* d_in, const int* in_sizes, int n_in,
                              void* d_out, int out_size, void* d_ws, size_t ws_size,
                              hipStream_t stream) {
    const float* x     = (const float*)d_in[0];
    const float* alpha = (const float*)d_in[1];
    const float* beta  = (const float*)d_in[2];
    const float* upf   = (const float*)d_in[3];
    const float* downf = (const float*)d_in[4];
    float* out = (float*)d_out;

    const int C    = in_sizes[1];             // 512
    const int rows = in_sizes[0] / T_LEN;     // B*C = 8192

    dim3 grid(rows), block(NT);
    hipLaunchKernelGGL(aa_act_kernel, grid, block, 0, stream,
                       x, alpha, beta, upf, downf, out, C);
}